// Round 8
// baseline (154.070 us; speedup 1.0000x reference)
//
#include <hip/hip_runtime.h>

#define DIM_ 1024
#define HEADS_ 16
#define HD_ 64
#define T_ 2048
#define BATCH_ 2
#define QKVN_ 3072

typedef unsigned short u16;
typedef unsigned int u32;
typedef float f32x4 __attribute__((ext_vector_type(4)));
typedef float f32x16 __attribute__((ext_vector_type(16)));
typedef short s16x8 __attribute__((ext_vector_type(8)));
typedef unsigned short u16x4 __attribute__((ext_vector_type(4)));

__device__ __forceinline__ u16 f2bf(float f) {
  unsigned u = __float_as_uint(f);
  u += 0x7fffu + ((u >> 16) & 1u);
  return (u16)(u >> 16);
}

__device__ __forceinline__ float fexp2(float x) {
  float r;
  asm("v_exp_f32 %0, %1" : "=v"(r) : "v"(x));
  return r;
}

__device__ __forceinline__ u32 cvtpk(float a, float b) {
  u32 r;
  asm("v_cvt_pk_bf16_f32 %0, %1, %2" : "=v"(r) : "v"(a), "v"(b));
  return r;
}

// ---------------- fused fp32 -> bf16 conversion (x | w_qkv | w_out) ----------------
__global__ __launch_bounds__(256) void cvt_all(const float* __restrict__ x,
                                               const float* __restrict__ wqkv,
                                               const float* __restrict__ wout,
                                               u16* __restrict__ outbase) {
  int i = blockIdx.x * 256 + threadIdx.x;   // [0, 2097152)
  const float4* src;
  int off;
  if (i < 1048576) { src = (const float4*)x; off = i; }
  else if (i < 1835008) { src = (const float4*)wqkv; off = i - 1048576; }
  else { src = (const float4*)wout; off = i - 1835008; }
  float4 v = src[off];
  u16x4 o;
  o.x = f2bf(v.x); o.y = f2bf(v.y); o.z = f2bf(v.z); o.w = f2bf(v.w);
  reinterpret_cast<u16x4*>(outbase)[i] = o;
}

// ---------------- async global->LDS helper ----------------
__device__ __forceinline__ void gld_lds16(const void* g, void* l) {
  auto gp = (__attribute__((address_space(1))) char*)(unsigned long long)g;
  auto lp = (__attribute__((address_space(3))) char*)(unsigned int)(unsigned long long)l;
  __builtin_amdgcn_global_load_lds(gp, lp, 16, 0, 0);
}

// ---------------- GEMM: C[M][N] = A[M][K] * B[N][K]^T (bf16 in, fp32 acc) ----------------
template <int OUTF32>
__global__ __launch_bounds__(256) void gemm_bt(const u16* __restrict__ A,
                                               const u16* __restrict__ B,
                                               void* __restrict__ Cv,
                                               int M, int N, int K) {
  __shared__ __align__(16) u16 As[128 * 32];
  __shared__ __align__(16) u16 Bs[128 * 32];
  const int tid = threadIdx.x;
  const int lane = tid & 63;
  const int w = tid >> 6;
  const int wr = w >> 1, wc = w & 1;
  const int lrow = lane & 15, kg = lane >> 4;
  const int nt = blockIdx.x, mt = blockIdx.y;
  const u16* Ag = A + (size_t)(mt * 128) * K;
  const u16* Bg = B + (size_t)(nt * 128) * K;

  f32x4 acc[4][4];
#pragma unroll
  for (int i = 0; i < 4; ++i)
#pragma unroll
    for (int j = 0; j < 4; ++j) {
      f32x4 z = {0.f, 0.f, 0.f, 0.f};
      acc[i][j] = z;
    }

  const int e0 = tid * 8;
  const int row0 = e0 >> 5, kc0 = e0 & 31;
  const int row1 = row0 + 64, kc1 = kc0;
  const int ldsoff0 = (tid & ~63) * 16;
  const int ldsoff1 = (256 + (tid & ~63)) * 16;

  for (int k0 = 0; k0 < K; k0 += 32) {
    gld_lds16(Ag + (size_t)row0 * K + k0 + kc0, (char*)As + ldsoff0);
    gld_lds16(Ag + (size_t)row1 * K + k0 + kc1, (char*)As + ldsoff1);
    gld_lds16(Bg + (size_t)row0 * K + k0 + kc0, (char*)Bs + ldsoff0);
    gld_lds16(Bg + (size_t)row1 * K + k0 + kc1, (char*)Bs + ldsoff1);
    __syncthreads();
    s16x8 a[4], b[4];
#pragma unroll
    for (int mf = 0; mf < 4; ++mf)
      a[mf] = *(const s16x8*)&As[(wr * 64 + mf * 16 + lrow) * 32 + 8 * kg];
#pragma unroll
    for (int nf = 0; nf < 4; ++nf)
      b[nf] = *(const s16x8*)&Bs[(wc * 64 + nf * 16 + lrow) * 32 + 8 * kg];
#pragma unroll
    for (int mf = 0; mf < 4; ++mf)
#pragma unroll
      for (int nf = 0; nf < 4; ++nf)
        acc[mf][nf] = __builtin_amdgcn_mfma_f32_16x16x32_bf16(a[mf], b[nf], acc[mf][nf], 0, 0, 0);
    __syncthreads();
  }

#pragma unroll
  for (int mf = 0; mf < 4; ++mf)
#pragma unroll
    for (int nf = 0; nf < 4; ++nf)
#pragma unroll
      for (int j = 0; j < 4; ++j) {
        int r = mt * 128 + wr * 64 + mf * 16 + 4 * kg + j;
        int c = nt * 128 + wc * 64 + nf * 16 + lrow;
        float v = acc[mf][nf][j];
        if (OUTF32) ((float*)Cv)[(size_t)r * N + c] = v;
        else        ((u16*)Cv)[(size_t)r * N + c] = f2bf(v);
      }
}

// ---------------- V transpose: vt[b][h][d][t] = qkv[b*T+t][2048 + h*64 + d] ----------------
__global__ __launch_bounds__(256) void transpose_v(const u16* __restrict__ qkv,
                                                   u16* __restrict__ vt) {
  const int tt = blockIdx.x, bh = blockIdx.y;
  const int b = bh >> 4, h = bh & 15;
  const int d = threadIdx.x & 63;
  const int t16 = threadIdx.x >> 6;
  const int tbase = tt * 64 + t16 * 16;
  u16 tmp[16];
#pragma unroll
  for (int i = 0; i < 16; ++i)
    tmp[i] = qkv[(size_t)(b * T_ + tbase + i) * QKVN_ + 2048 + h * 64 + d];
  u16* dst = vt + (size_t)(bh * 64 + d) * T_ + tbase;
  *(s16x8*)dst = *(const s16x8*)tmp;
  *(s16x8*)(dst + 8) = *(const s16x8*)(tmp + 8);
}

// ---------------- causal flash attention (barrier-free, direct-L2, kv-split-4) ----------
// 2048 blocks (64 j-tiles desc x 32 bh), 256 threads = 4 independent waves.
// Wave kvg owns q rows [j*32, +32) and kv tiles t = kvg, kvg+4, ... No LDS in main
// loop; K/V fragments read directly from global (L2/L3-resident). 4-way partial
// merge at the end through 26 KB LDS.
__global__ __launch_bounds__(256, 3) void attn_fwd(const u16* __restrict__ qkv,
                                                   const u16* __restrict__ vt,
                                                   u16* __restrict__ o) {
  const int gid = blockIdx.x;
  const int j = 63 - (gid >> 5);       // long q-tiles first
  const int bh = gid & 31;
  const int b = bh >> 4, h = bh & 15;
  const int tid = threadIdx.x;
  const int kvg = tid >> 6;            // 0..3
  const int lane = tid & 63;
  const int l31 = lane & 31, hi = lane >> 5;
  const int qrow0 = j * 32;
  const int woff = (j & 1) * 32;       // q offset within the 64-wide diag kv tile
  const int nt = (j >> 1) + 1;         // kv tiles needed

  __shared__ __align__(16) f32x4 OmT[3][8][64];   // partials O (24 KB)
  __shared__ float Mm[3][64], Lm[3][64];

  const u16* Kl = qkv + (size_t)(b * T_ + l31) * QKVN_ + 1024 + h * 64 + 8 * hi;
  const u16* Vl = vt + (size_t)(bh * 64 + l31) * T_ + 8 * hi;

  // Q fragments: lane (l31,hi) holds Q[qrow0+l31][16*ksl + 8*hi .. +8]
  s16x8 qf[4];
  {
    const u16* qp = qkv + (size_t)(b * T_ + qrow0 + l31) * QKVN_ + h * 64 + 8 * hi;
#pragma unroll
    for (int ksl = 0; ksl < 4; ++ksl)
      qf[ksl] = *(const s16x8*)(qp + 16 * ksl);
  }

  f32x16 o0v, o1v;
#pragma unroll
  for (int r = 0; r < 16; ++r) { o0v[r] = 0.f; o1v[r] = 0.f; }
  float mrun = -__builtin_inff(), lrun = 0.0f;
  const float CEXP = 0.18033688011112042f;  // (1/8) * log2(e)

  for (int t = kvg; t < nt; t += 4) {
    const bool isdiag = (t == nt - 1);
    const bool two = !(isdiag && woff == 0);
    const u16* Kt = Kl + (size_t)(t * 64) * QKVN_;
    const u16* Vt = Vl + t * 64;

    // ---- K fragment loads (direct global, 128B-aligned row slices) ----
    s16x8 k0[4], k1[4];
#pragma unroll
    for (int ksl = 0; ksl < 4; ++ksl)
      k0[ksl] = *(const s16x8*)(Kt + 16 * ksl);
    if (two) {
#pragma unroll
      for (int ksl = 0; ksl < 4; ++ksl)
        k1[ksl] = *(const s16x8*)(Kt + (size_t)32 * QKVN_ + 16 * ksl);
    }

    // ---- QK^T (swapped): lane holds q = qrow0+l31 ----
    f32x16 s0v, s1v;
#pragma unroll
    for (int r = 0; r < 16; ++r) { s0v[r] = 0.f; s1v[r] = 0.f; }
    __builtin_amdgcn_s_setprio(1);
#pragma unroll
    for (int ksl = 0; ksl < 4; ++ksl)
      s0v = __builtin_amdgcn_mfma_f32_32x32x16_bf16(k0[ksl], qf[ksl], s0v, 0, 0, 0);
    if (two) {
#pragma unroll
      for (int ksl = 0; ksl < 4; ++ksl)
        s1v = __builtin_amdgcn_mfma_f32_32x32x16_bf16(k1[ksl], qf[ksl], s1v, 0, 0, 0);
    }
    __builtin_amdgcn_s_setprio(0);

    // ---- causal mask (diagonal tile only) ----
    if (isdiag) {
      const int thr = woff + l31;
#pragma unroll
      for (int r = 0; r < 16; ++r) {
        const int kvl = 4 * hi + (r & 3) + 8 * (r >> 2);
        if (kvl > thr) s0v[r] = -__builtin_inff();
        if (two && kvl + 32 > thr) s1v[r] = -__builtin_inff();
      }
    }

    // ---- online softmax, per-lane ----
    float mloc = s0v[0];
#pragma unroll
    for (int r = 1; r < 16; ++r) mloc = fmaxf(mloc, s0v[r]);
    if (two) {
#pragma unroll
      for (int r = 0; r < 16; ++r) mloc = fmaxf(mloc, s1v[r]);
    }
    mloc = fmaxf(mloc, __shfl_xor(mloc, 32));

    const bool needfull = !((mloc - mrun) * CEXP <= 8.0f);
    if (__any(needfull)) {
      const float newm = fmaxf(mrun, mloc);
      const float sc = fexp2((mrun - newm) * CEXP);
      mrun = newm;
      lrun *= sc;
      o0v *= sc;
      o1v *= sc;
    }
    const float msc = mrun * CEXP;

    float rs = 0.0f;
    u32 pd0[8], pd1[8];
#pragma unroll
    for (int ri = 0; ri < 8; ++ri) {
      const float p0 = fexp2(__builtin_fmaf(s0v[2 * ri], CEXP, -msc));
      const float p1 = fexp2(__builtin_fmaf(s0v[2 * ri + 1], CEXP, -msc));
      rs += p0 + p1;
      pd0[ri] = cvtpk(p0, p1);
    }
    if (two) {
#pragma unroll
      for (int ri = 0; ri < 8; ++ri) {
        const float p0 = fexp2(__builtin_fmaf(s1v[2 * ri], CEXP, -msc));
        const float p1 = fexp2(__builtin_fmaf(s1v[2 * ri + 1], CEXP, -msc));
        rs += p0 + p1;
        pd1[ri] = cvtpk(p0, p1);
      }
    }
    rs += __shfl_xor(rs, 32);
    lrun += rs;

    // ---- PV: rebuild B-fragments in-register; V direct from global ----
    __builtin_amdgcn_s_setprio(1);
#pragma unroll
    for (int kk = 0; kk < 4; ++kk) {
      if (kk >= 2 && !two) break;
      u32 x0, y0, x1, y1;
      if (kk == 0)      { x0 = pd0[0]; y0 = pd0[2]; x1 = pd0[1]; y1 = pd0[3]; }
      else if (kk == 1) { x0 = pd0[4]; y0 = pd0[6]; x1 = pd0[5]; y1 = pd0[7]; }
      else if (kk == 2) { x0 = pd1[0]; y0 = pd1[2]; x1 = pd1[1]; y1 = pd1[3]; }
      else              { x0 = pd1[4]; y0 = pd1[6]; x1 = pd1[5]; y1 = pd1[7]; }
      asm volatile("v_permlane32_swap_b32 %0, %1" : "+v"(x0), "+v"(y0));
      asm volatile("v_permlane32_swap_b32 %0, %1" : "+v"(x1), "+v"(y1));
      u32 pw[4] = {x0, x1, y0, y1};
      const s16x8 pf = *(const s16x8*)pw;
      const s16x8 vf0 = *(const s16x8*)(Vt + 16 * kk);
      const s16x8 vf1 = *(const s16x8*)(Vt + (size_t)32 * T_ + 16 * kk);
      o0v = __builtin_amdgcn_mfma_f32_32x32x16_bf16(vf0, pf, o0v, 0, 0, 0);
      o1v = __builtin_amdgcn_mfma_f32_32x32x16_bf16(vf1, pf, o1v, 0, 0, 0);
    }
    __builtin_amdgcn_s_setprio(0);
  }

  // ---- merge the 4 kv-split partials ----
  if (kvg != 0) {
#pragma unroll
    for (int c = 0; c < 4; ++c) {
      f32x4 v0 = {o0v[4 * c], o0v[4 * c + 1], o0v[4 * c + 2], o0v[4 * c + 3]};
      f32x4 v1 = {o1v[4 * c], o1v[4 * c + 1], o1v[4 * c + 2], o1v[4 * c + 3]};
      OmT[kvg - 1][c][lane] = v0;
      OmT[kvg - 1][4 + c][lane] = v1;
    }
    Mm[kvg - 1][lane] = mrun;
    Lm[kvg - 1][lane] = lrun;
  }
  __syncthreads();
  if (kvg == 0) {
    float mp[3], lp[3];
#pragma unroll
    for (int p = 0; p < 3; ++p) { mp[p] = Mm[p][lane]; lp[p] = Lm[p][lane]; }
    float m2 = mrun;
#pragma unroll
    for (int p = 0; p < 3; ++p) m2 = fmaxf(m2, mp[p]);
    const float s0 = fexp2((mrun - m2) * CEXP);
    float ltot = lrun * s0;
    float sp[3];
#pragma unroll
    for (int p = 0; p < 3; ++p) { sp[p] = fexp2((mp[p] - m2) * CEXP); ltot += lp[p] * sp[p]; }

    float num[32];
#pragma unroll
    for (int r = 0; r < 16; ++r) { num[r] = o0v[r] * s0; num[16 + r] = o1v[r] * s0; }
#pragma unroll
    for (int p = 0; p < 3; ++p)
#pragma unroll
      for (int c = 0; c < 8; ++c) {
        f32x4 vc = OmT[p][c][lane];
#pragma unroll
        for (int i = 0; i < 4; ++i) num[4 * c + i] += vc[i] * sp[p];
      }

    const float linv = 1.0f / ltot;
    u16* orow = o + (size_t)(b * T_ + qrow0 + l31) * DIM_ + h * 64;
#pragma unroll
    for (int ri = 0; ri < 8; ++ri) {
      const int dbase0 = 4 * hi + 8 * (ri >> 1) + 2 * (ri & 1);
      *(u32*)(orow + dbase0) = cvtpk(num[2 * ri] * linv, num[2 * ri + 1] * linv);
      *(u32*)(orow + 32 + dbase0) = cvtpk(num[16 + 2 * ri] * linv, num[16 + 2 * ri + 1] * linv);
    }
  }
}

// ---------------- launch ----------------
extern "C" void kernel_launch(void* const* d_in, const int* in_sizes, int n_in,
                              void* d_out, int out_size, void* d_ws, size_t ws_size,
                              hipStream_t stream) {
  const float* x = (const float*)d_in[0];
  const float* w_qkv = (const float*)d_in[1];
  const float* w_out = (const float*)d_in[2];
  char* ws = (char*)d_ws;
  u16* xb    = (u16*)(ws + 0);          // 8,388,608
  u16* wqkvb = (u16*)(ws + 8388608);    // 6,291,456
  u16* woutb = (u16*)(ws + 14680064);   // 2,097,152
  u16* qkvb  = (u16*)(ws + 16777216);   // 25,165,824
  u16* vtb   = (u16*)(ws + 41943040);   // 8,388,608
  u16* attno = (u16*)(ws + 50331648);   // 8,388,608

  cvt_all<<<8192, 256, 0, stream>>>(x, w_qkv, w_out, xb);
  gemm_bt<0><<<dim3(24, 32), 256, 0, stream>>>(xb, wqkvb, qkvb, 4096, 3072, 1024);
  transpose_v<<<dim3(32, 32), 256, 0, stream>>>(qkvb, vtb);
  attn_fwd<<<2048, 256, 0, stream>>>(qkvb, vtb, attno);
  gemm_bt<1><<<dim3(8, 32), 256, 0, stream>>>(attno, woutb, (float*)d_out, 4096, 1024, 1024);
}

// Round 9
// 112.412 us; speedup vs baseline: 1.3706x; 1.3706x over previous
//
#include <hip/hip_runtime.h>

#define DIM_ 1024
#define HEADS_ 16
#define HD_ 64
#define T_ 2048
#define BATCH_ 2
#define QKVN_ 3072

typedef unsigned short u16;
typedef unsigned int u32;
typedef float f32x4 __attribute__((ext_vector_type(4)));
typedef float f32x16 __attribute__((ext_vector_type(16)));
typedef short s16x8 __attribute__((ext_vector_type(8)));
typedef unsigned short u16x4 __attribute__((ext_vector_type(4)));

__device__ __forceinline__ u16 f2bf(float f) {
  unsigned u = __float_as_uint(f);
  u += 0x7fffu + ((u >> 16) & 1u);
  return (u16)(u >> 16);
}

__device__ __forceinline__ float fexp2(float x) {
  float r;
  asm("v_exp_f32 %0, %1" : "=v"(r) : "v"(x));
  return r;
}

__device__ __forceinline__ u32 cvtpk(float a, float b) {
  u32 r;
  asm("v_cvt_pk_bf16_f32 %0, %1, %2" : "=v"(r) : "v"(a), "v"(b));
  return r;
}

// ---------------- fused fp32 -> bf16 conversion (x | w_qkv | w_out) ----------------
__global__ __launch_bounds__(256) void cvt_all(const float* __restrict__ x,
                                               const float* __restrict__ wqkv,
                                               const float* __restrict__ wout,
                                               u16* __restrict__ outbase) {
  int i = blockIdx.x * 256 + threadIdx.x;   // [0, 2097152)
  const float4* src;
  int off;
  if (i < 1048576) { src = (const float4*)x; off = i; }
  else if (i < 1835008) { src = (const float4*)wqkv; off = i - 1048576; }
  else { src = (const float4*)wout; off = i - 1835008; }
  float4 v = src[off];
  u16x4 o;
  o.x = f2bf(v.x); o.y = f2bf(v.y); o.z = f2bf(v.z); o.w = f2bf(v.w);
  reinterpret_cast<u16x4*>(outbase)[i] = o;
}

// ---------------- async global->LDS helper ----------------
__device__ __forceinline__ void gld_lds16(const void* g, void* l) {
  auto gp = (__attribute__((address_space(1))) char*)(unsigned long long)g;
  auto lp = (__attribute__((address_space(3))) char*)(unsigned int)(unsigned long long)l;
  __builtin_amdgcn_global_load_lds(gp, lp, 16, 0, 0);
}

// ---------------- QKV GEMM: qkv[M][3072] = x * Wqkv^T, V third written transposed ----
__global__ __launch_bounds__(256) void gemm_qkv(const u16* __restrict__ A,
                                                const u16* __restrict__ B,
                                                u16* __restrict__ qkvo,
                                                u16* __restrict__ vto,
                                                int M, int N, int K) {
  __shared__ __align__(16) u16 As[128 * 32];
  __shared__ __align__(16) u16 Bs[128 * 32];
  const int tid = threadIdx.x;
  const int lane = tid & 63;
  const int w = tid >> 6;
  const int wr = w >> 1, wc = w & 1;
  const int lrow = lane & 15, kg = lane >> 4;
  const int nt = blockIdx.x, mt = blockIdx.y;
  const u16* Ag = A + (size_t)(mt * 128) * K;
  const u16* Bg = B + (size_t)(nt * 128) * K;

  f32x4 acc[4][4];
#pragma unroll
  for (int i = 0; i < 4; ++i)
#pragma unroll
    for (int j = 0; j < 4; ++j) {
      f32x4 z = {0.f, 0.f, 0.f, 0.f};
      acc[i][j] = z;
    }

  const int e0 = tid * 8;
  const int row0 = e0 >> 5, kc0 = e0 & 31;
  const int row1 = row0 + 64, kc1 = kc0;
  const int ldsoff0 = (tid & ~63) * 16;
  const int ldsoff1 = (256 + (tid & ~63)) * 16;

  for (int k0 = 0; k0 < K; k0 += 32) {
    gld_lds16(Ag + (size_t)row0 * K + k0 + kc0, (char*)As + ldsoff0);
    gld_lds16(Ag + (size_t)row1 * K + k0 + kc1, (char*)As + ldsoff1);
    gld_lds16(Bg + (size_t)row0 * K + k0 + kc0, (char*)Bs + ldsoff0);
    gld_lds16(Bg + (size_t)row1 * K + k0 + kc1, (char*)Bs + ldsoff1);
    __syncthreads();
    s16x8 a[4], b[4];
#pragma unroll
    for (int mf = 0; mf < 4; ++mf)
      a[mf] = *(const s16x8*)&As[(wr * 64 + mf * 16 + lrow) * 32 + 8 * kg];
#pragma unroll
    for (int nf = 0; nf < 4; ++nf)
      b[nf] = *(const s16x8*)&Bs[(wc * 64 + nf * 16 + lrow) * 32 + 8 * kg];
#pragma unroll
    for (int mf = 0; mf < 4; ++mf)
#pragma unroll
      for (int nf = 0; nf < 4; ++nf)
        acc[mf][nf] = __builtin_amdgcn_mfma_f32_16x16x32_bf16(a[mf], b[nf], acc[mf][nf], 0, 0, 0);
    __syncthreads();
  }

  if (nt < 16) {       // Q,K thirds: row-major into qkv buffer
#pragma unroll
    for (int mf = 0; mf < 4; ++mf)
#pragma unroll
      for (int nf = 0; nf < 4; ++nf)
#pragma unroll
        for (int j = 0; j < 4; ++j) {
          int r = mt * 128 + wr * 64 + mf * 16 + 4 * kg + j;
          int c = nt * 128 + wc * 64 + nf * 16 + lrow;
          qkvo[(size_t)r * QKVN_ + c] = f2bf(acc[mf][nf][j]);
        }
  } else {             // V third: write transposed vt[b][h][d][t]
#pragma unroll
    for (int mf = 0; mf < 4; ++mf)
#pragma unroll
      for (int nf = 0; nf < 4; ++nf) {
        const int c = nt * 128 + wc * 64 + nf * 16 + lrow;   // 2048..3071
        const int d = c & 63, hV = (c >> 6) & 15;
        const int r0 = mt * 128 + wr * 64 + mf * 16 + 4 * kg;
        const int bb = r0 >> 11, t0 = r0 & 2047;
        u16x4 pk;
        pk.x = f2bf(acc[mf][nf][0]); pk.y = f2bf(acc[mf][nf][1]);
        pk.z = f2bf(acc[mf][nf][2]); pk.w = f2bf(acc[mf][nf][3]);
        *(u16x4*)(vto + ((size_t)(bb * 16 + hV) * 64 + d) * T_ + t0) = pk;
      }
  }
}

// ---------------- out-proj GEMM: C[M][N] = A[M][K] * B[N][K]^T, f32 out ----------------
__global__ __launch_bounds__(256) void gemm_out(const u16* __restrict__ A,
                                                const u16* __restrict__ B,
                                                float* __restrict__ Cv,
                                                int M, int N, int K) {
  __shared__ __align__(16) u16 As[128 * 32];
  __shared__ __align__(16) u16 Bs[128 * 32];
  const int tid = threadIdx.x;
  const int lane = tid & 63;
  const int w = tid >> 6;
  const int wr = w >> 1, wc = w & 1;
  const int lrow = lane & 15, kg = lane >> 4;
  const int nt = blockIdx.x, mt = blockIdx.y;
  const u16* Ag = A + (size_t)(mt * 128) * K;
  const u16* Bg = B + (size_t)(nt * 128) * K;

  f32x4 acc[4][4];
#pragma unroll
  for (int i = 0; i < 4; ++i)
#pragma unroll
    for (int j = 0; j < 4; ++j) {
      f32x4 z = {0.f, 0.f, 0.f, 0.f};
      acc[i][j] = z;
    }

  const int e0 = tid * 8;
  const int row0 = e0 >> 5, kc0 = e0 & 31;
  const int row1 = row0 + 64, kc1 = kc0;
  const int ldsoff0 = (tid & ~63) * 16;
  const int ldsoff1 = (256 + (tid & ~63)) * 16;

  for (int k0 = 0; k0 < K; k0 += 32) {
    gld_lds16(Ag + (size_t)row0 * K + k0 + kc0, (char*)As + ldsoff0);
    gld_lds16(Ag + (size_t)row1 * K + k0 + kc1, (char*)As + ldsoff1);
    gld_lds16(Bg + (size_t)row0 * K + k0 + kc0, (char*)Bs + ldsoff0);
    gld_lds16(Bg + (size_t)row1 * K + k0 + kc1, (char*)Bs + ldsoff1);
    __syncthreads();
    s16x8 a[4], b[4];
#pragma unroll
    for (int mf = 0; mf < 4; ++mf)
      a[mf] = *(const s16x8*)&As[(wr * 64 + mf * 16 + lrow) * 32 + 8 * kg];
#pragma unroll
    for (int nf = 0; nf < 4; ++nf)
      b[nf] = *(const s16x8*)&Bs[(wc * 64 + nf * 16 + lrow) * 32 + 8 * kg];
#pragma unroll
    for (int mf = 0; mf < 4; ++mf)
#pragma unroll
      for (int nf = 0; nf < 4; ++nf)
        acc[mf][nf] = __builtin_amdgcn_mfma_f32_16x16x32_bf16(a[mf], b[nf], acc[mf][nf], 0, 0, 0);
    __syncthreads();
  }

#pragma unroll
  for (int mf = 0; mf < 4; ++mf)
#pragma unroll
    for (int nf = 0; nf < 4; ++nf)
#pragma unroll
      for (int j = 0; j < 4; ++j) {
        int r = mt * 128 + wr * 64 + mf * 16 + 4 * kg + j;
        int c = nt * 128 + wc * 64 + nf * 16 + lrow;
        Cv[(size_t)r * N + c] = acc[mf][nf][j];
      }
}

// ---------------- causal flash attention (paired q-tiles, uniform blocks) ----------------
// 512 blocks (16 pairs x 32 bh), 256 threads = 2 q-subwaves x 2 kv-parities.
// Block handles q-tiles jt = 31-p then p (64 rows each) -> 17 staging rounds uniform.
// K/V double-buffered in 64 KB LDS (slot^row&7 swizzle), kv-split-2 merge per phase.
__global__ __launch_bounds__(256, 2) void attn_fwd(const u16* __restrict__ qkv,
                                                   const u16* __restrict__ vt,
                                                   u16* __restrict__ o) {
  const int gid = blockIdx.x;
  const int pr = gid >> 5;             // 0..15
  const int bh = gid & 31;
  const int b = bh >> 4, h = bh & 15;
  const int tid = threadIdx.x;
  const int lane = tid & 63;
  const int qw = (tid >> 6) & 1;       // q-subwave (32 rows)
  const int kvg = tid >> 7;            // kv parity
  const int l31 = lane & 31, hi = lane >> 5;

  // K: smem + buf*16384 + par*8192 ; V: +32768 same
  __shared__ __align__(16) char smem[65536];

  const int row_s = tid >> 3, slot_s = tid & 7;
  const u16* Kbase = qkv + (size_t)(b * T_) * QKVN_ + 1024 + h * 64;
  const u16* Vbase = vt + (size_t)(bh * 64) * T_;
  const u16* KgA = Kbase + (size_t)row_s * QKVN_ + slot_s * 8;
  const u16* KgB = KgA + (size_t)32 * QKVN_;
  const u16* VgA = Vbase + (size_t)row_s * T_ + slot_s * 8;
  const u16* VgB = VgA + (size_t)32 * T_;
  const int dstA = row_s * 128 + ((slot_s ^ (row_s & 7)) << 4);  // +4096 for chunk B

  const int rbyte = l31 * 128;
  const int xsw = l31 & 7;
  const float CEXP = 0.18033688011112042f;  // (1/8) * log2(e)

  for (int ph = 0; ph < 2; ++ph) {
    const int jt = (ph == 0) ? (31 - pr) : pr;
    const int nt = jt + 1;
    const int nrt = (nt + 1) >> 1;
    const int qrow0 = 64 * jt + 32 * qw;

    // Q fragments: lane (l31,hi) holds Q[qrow0+l31][16*ksl + 8*hi .. +8]
    s16x8 qf[4];
    {
      const u16* qp = qkv + (size_t)(b * T_ + qrow0 + l31) * QKVN_ + h * 64 + 8 * hi;
#pragma unroll
      for (int ksl = 0; ksl < 4; ++ksl)
        qf[ksl] = *(const s16x8*)(qp + 16 * ksl);
    }

    f32x16 o0v, o1v;
#pragma unroll
    for (int r = 0; r < 16; ++r) { o0v[r] = 0.f; o1v[r] = 0.f; }
    float mrun = -__builtin_inff(), lrun = 0.0f;

    __syncthreads();   // smem free (prev phase merge fully read)
    // prologue: stage tiles 0 (and 1) into buf 0
    *(s16x8*)(smem + dstA)                 = *(const s16x8*)KgA;
    *(s16x8*)(smem + 4096 + dstA)          = *(const s16x8*)KgB;
    *(s16x8*)(smem + 32768 + dstA)         = *(const s16x8*)VgA;
    *(s16x8*)(smem + 32768 + 4096 + dstA)  = *(const s16x8*)VgB;
    if (nt > 1) {
      *(s16x8*)(smem + 8192 + dstA)                = *(const s16x8*)(KgA + (size_t)64 * QKVN_);
      *(s16x8*)(smem + 8192 + 4096 + dstA)         = *(const s16x8*)(KgB + (size_t)64 * QKVN_);
      *(s16x8*)(smem + 32768 + 8192 + dstA)        = *(const s16x8*)(VgA + 64);
      *(s16x8*)(smem + 32768 + 8192 + 4096 + dstA) = *(const s16x8*)(VgB + 64);
    }

    int cur = 0;
    for (int r = 0; r < nrt; ++r) {
      const int t = 2 * r + kvg;
      const bool pe = (2 * r + 2 < nt), po = (2 * r + 3 < nt);
      s16x8 ke0, ke1, ve0, ve1, ko0, ko1, vo0, vo1;
      if (pe) {                         // issue next-round loads early
        const size_t kofs = (size_t)(2 * r + 2) * 64 * QKVN_;
        const int vofs = (2 * r + 2) * 64;
        ke0 = *(const s16x8*)(KgA + kofs);
        ke1 = *(const s16x8*)(KgB + kofs);
        ve0 = *(const s16x8*)(VgA + vofs);
        ve1 = *(const s16x8*)(VgB + vofs);
      }
      if (po) {
        const size_t kofs = (size_t)(2 * r + 3) * 64 * QKVN_;
        const int vofs = (2 * r + 3) * 64;
        ko0 = *(const s16x8*)(KgA + kofs);
        ko1 = *(const s16x8*)(KgB + kofs);
        vo0 = *(const s16x8*)(VgA + vofs);
        vo1 = *(const s16x8*)(VgB + vofs);
      }
      __syncthreads();

      if (t < nt) {
        const char* Kc = smem + cur * 16384 + kvg * 8192;
        const char* Vc = smem + 32768 + cur * 16384 + kvg * 8192;
        const bool isdiag = (t == nt - 1);
        const bool two = !(isdiag && qw == 0);

        // ---- QK^T (swapped): lane holds q = qrow0+l31 ----
        f32x16 s0v, s1v;
#pragma unroll
        for (int rr = 0; rr < 16; ++rr) { s0v[rr] = 0.f; s1v[rr] = 0.f; }
        __builtin_amdgcn_s_setprio(1);
#pragma unroll
        for (int ksl = 0; ksl < 4; ++ksl) {
          const s16x8 kf = *(const s16x8*)(Kc + rbyte + (((2 * ksl + hi) ^ xsw) << 4));
          s0v = __builtin_amdgcn_mfma_f32_32x32x16_bf16(kf, qf[ksl], s0v, 0, 0, 0);
        }
        if (two) {
#pragma unroll
          for (int ksl = 0; ksl < 4; ++ksl) {
            const s16x8 kf = *(const s16x8*)(Kc + 4096 + rbyte + (((2 * ksl + hi) ^ xsw) << 4));
            s1v = __builtin_amdgcn_mfma_f32_32x32x16_bf16(kf, qf[ksl], s1v, 0, 0, 0);
          }
        }
        __builtin_amdgcn_s_setprio(0);

        // ---- causal mask (diagonal tile only) ----
        if (isdiag) {
          const int thr = 32 * qw + l31;
#pragma unroll
          for (int rr = 0; rr < 16; ++rr) {
            const int kvl = 4 * hi + (rr & 3) + 8 * (rr >> 2);
            if (kvl > thr) s0v[rr] = -__builtin_inff();
            if (two && kvl + 32 > thr) s1v[rr] = -__builtin_inff();
          }
        }

        // ---- online softmax, per-lane ----
        float mloc = s0v[0];
#pragma unroll
        for (int rr = 1; rr < 16; ++rr) mloc = fmaxf(mloc, s0v[rr]);
        if (two) {
#pragma unroll
          for (int rr = 0; rr < 16; ++rr) mloc = fmaxf(mloc, s1v[rr]);
        }
        mloc = fmaxf(mloc, __shfl_xor(mloc, 32));

        const bool needfull = !((mloc - mrun) * CEXP <= 8.0f);
        if (__any(needfull)) {
          const float newm = fmaxf(mrun, mloc);
          const float sc = fexp2((mrun - newm) * CEXP);
          mrun = newm;
          lrun *= sc;
          o0v *= sc;
          o1v *= sc;
        }
        const float msc = mrun * CEXP;

        float rs = 0.0f;
        u32 pd0[8], pd1[8];
#pragma unroll
        for (int ri = 0; ri < 8; ++ri) {
          const float p0 = fexp2(__builtin_fmaf(s0v[2 * ri], CEXP, -msc));
          const float p1 = fexp2(__builtin_fmaf(s0v[2 * ri + 1], CEXP, -msc));
          rs += p0 + p1;
          pd0[ri] = cvtpk(p0, p1);
        }
        if (two) {
#pragma unroll
          for (int ri = 0; ri < 8; ++ri) {
            const float p0 = fexp2(__builtin_fmaf(s1v[2 * ri], CEXP, -msc));
            const float p1 = fexp2(__builtin_fmaf(s1v[2 * ri + 1], CEXP, -msc));
            rs += p0 + p1;
            pd1[ri] = cvtpk(p0, p1);
          }
        }
        rs += __shfl_xor(rs, 32);
        lrun += rs;

        // ---- PV: rebuild B-fragments in-register, accumulate O^T ----
        __builtin_amdgcn_s_setprio(1);
#pragma unroll
        for (int kk = 0; kk < 4; ++kk) {
          if (kk >= 2 && !two) break;
          u32 x0, y0, x1, y1;
          if (kk == 0)      { x0 = pd0[0]; y0 = pd0[2]; x1 = pd0[1]; y1 = pd0[3]; }
          else if (kk == 1) { x0 = pd0[4]; y0 = pd0[6]; x1 = pd0[5]; y1 = pd0[7]; }
          else if (kk == 2) { x0 = pd1[0]; y0 = pd1[2]; x1 = pd1[1]; y1 = pd1[3]; }
          else              { x0 = pd1[4]; y0 = pd1[6]; x1 = pd1[5]; y1 = pd1[7]; }
          asm volatile("v_permlane32_swap_b32 %0, %1" : "+v"(x0), "+v"(y0));
          asm volatile("v_permlane32_swap_b32 %0, %1" : "+v"(x1), "+v"(y1));
          u32 pw[4] = {x0, x1, y0, y1};
          const s16x8 pf = *(const s16x8*)pw;
          const s16x8 vf0 = *(const s16x8*)(Vc + rbyte + (((2 * kk + hi) ^ xsw) << 4));
          const s16x8 vf1 = *(const s16x8*)(Vc + 4096 + rbyte + (((2 * kk + hi) ^ xsw) << 4));
          o0v = __builtin_amdgcn_mfma_f32_32x32x16_bf16(vf0, pf, o0v, 0, 0, 0);
          o1v = __builtin_amdgcn_mfma_f32_32x32x16_bf16(vf1, pf, o1v, 0, 0, 0);
        }
        __builtin_amdgcn_s_setprio(0);
      }

      if (pe) {                         // write-late into the other buffer set
        const int nb = (cur ^ 1) * 16384;
        *(s16x8*)(smem + nb + dstA)                = ke0;
        *(s16x8*)(smem + nb + 4096 + dstA)         = ke1;
        *(s16x8*)(smem + 32768 + nb + dstA)        = ve0;
        *(s16x8*)(smem + 32768 + nb + 4096 + dstA) = ve1;
      }
      if (po) {
        const int nb = (cur ^ 1) * 16384 + 8192;
        *(s16x8*)(smem + nb + dstA)                = ko0;
        *(s16x8*)(smem + nb + 4096 + dstA)         = ko1;
        *(s16x8*)(smem + 32768 + nb + dstA)        = vo0;
        *(s16x8*)(smem + 32768 + nb + 4096 + dstA) = vo1;
      }
      cur ^= 1;
    }

    // ---- merge kv-split pair partials (reuse LDS), write O ----
    __syncthreads();
    float* Om = (float*)smem + qw * 2048;            // 32 x 64 f32 per qw
    float* Mf = (float*)(smem + 16384) + qw * 64;
    float* Lf = (float*)(smem + 16896) + qw * 64;
    if (kvg == 1) {
#pragma unroll
      for (int rr = 0; rr < 16; ++rr) {
        Om[rr * 64 + lane] = o0v[rr];
        Om[(16 + rr) * 64 + lane] = o1v[rr];
      }
      Mf[lane] = mrun;
      Lf[lane] = lrun;
    }
    __syncthreads();
    if (kvg == 0) {
      const float mA = Mf[lane];
      const float lA = Lf[lane];
      const float m2 = fmaxf(mrun, mA);
      const float sB = fexp2((mrun - m2) * CEXP);
      const float sA = fexp2((mA - m2) * CEXP);
      const float linv = 1.0f / (lrun * sB + lA * sA);
      u16* orow = o + (size_t)(b * T_ + qrow0 + l31) * DIM_ + h * 64;
#pragma unroll
      for (int ri = 0; ri < 8; ++ri) {
        const int dbase0 = 4 * hi + 8 * (ri >> 1) + 2 * (ri & 1);
        const float a0 = (o0v[2 * ri] * sB + Om[(2 * ri) * 64 + lane] * sA) * linv;
        const float a1 = (o0v[2 * ri + 1] * sB + Om[(2 * ri + 1) * 64 + lane] * sA) * linv;
        const float c0 = (o1v[2 * ri] * sB + Om[(16 + 2 * ri) * 64 + lane] * sA) * linv;
        const float c1 = (o1v[2 * ri + 1] * sB + Om[(16 + 2 * ri + 1) * 64 + lane] * sA) * linv;
        *(u32*)(orow + dbase0) = cvtpk(a0, a1);
        *(u32*)(orow + 32 + dbase0) = cvtpk(c0, c1);
      }
    }
  }
}

// ---------------- launch ----------------
extern "C" void kernel_launch(void* const* d_in, const int* in_sizes, int n_in,
                              void* d_out, int out_size, void* d_ws, size_t ws_size,
                              hipStream_t stream) {
  const float* x = (const float*)d_in[0];
  const float* w_qkv = (const float*)d_in[1];
  const float* w_out = (const float*)d_in[2];
  char* ws = (char*)d_ws;
  u16* xb    = (u16*)(ws + 0);          // 8,388,608
  u16* wqkvb = (u16*)(ws + 8388608);    // 6,291,456
  u16* woutb = (u16*)(ws + 14680064);   // 2,097,152
  u16* qkvb  = (u16*)(ws + 16777216);   // 25,165,824 (V third unused)
  u16* vtb   = (u16*)(ws + 41943040);   // 8,388,608
  u16* attno = (u16*)(ws + 50331648);   // 8,388,608

  cvt_all<<<8192, 256, 0, stream>>>(x, w_qkv, w_out, xb);
  gemm_qkv<<<dim3(24, 32), 256, 0, stream>>>(xb, wqkvb, qkvb, vtb, 4096, 3072, 1024);
  attn_fwd<<<512, 256, 0, stream>>>(qkvb, vtb, attno);
  gemm_out<<<dim3(8, 32), 256, 0, stream>>>(attno, woutb, (float*)d_out, 4096, 1024, 1024);
}

// Round 10
// 105.188 us; speedup vs baseline: 1.4647x; 1.0687x over previous
//
#include <hip/hip_runtime.h>

#define DIM_ 1024
#define HEADS_ 16
#define HD_ 64
#define T_ 2048
#define BATCH_ 2
#define QKVN_ 3072

typedef unsigned short u16;
typedef unsigned int u32;
typedef float f32x4 __attribute__((ext_vector_type(4)));
typedef float f32x16 __attribute__((ext_vector_type(16)));
typedef short s16x8 __attribute__((ext_vector_type(8)));
typedef unsigned short u16x4 __attribute__((ext_vector_type(4)));

__device__ __forceinline__ u16 f2bf(float f) {
  unsigned u = __float_as_uint(f);
  u += 0x7fffu + ((u >> 16) & 1u);
  return (u16)(u >> 16);
}

__device__ __forceinline__ float fexp2(float x) {
  float r;
  asm("v_exp_f32 %0, %1" : "=v"(r) : "v"(x));
  return r;
}

__device__ __forceinline__ u32 cvtpk(float a, float b) {
  u32 r;
  asm("v_cvt_pk_bf16_f32 %0, %1, %2" : "=v"(r) : "v"(a), "v"(b));
  return r;
}

// ---------------- fused fp32 -> bf16 conversion (x | w_qkv | w_out) ----------------
__global__ __launch_bounds__(256) void cvt_all(const float* __restrict__ x,
                                               const float* __restrict__ wqkv,
                                               const float* __restrict__ wout,
                                               u16* __restrict__ outbase) {
  int i = blockIdx.x * 256 + threadIdx.x;   // [0, 2097152)
  const float4* src;
  int off;
  if (i < 1048576) { src = (const float4*)x; off = i; }
  else if (i < 1835008) { src = (const float4*)wqkv; off = i - 1048576; }
  else { src = (const float4*)wout; off = i - 1835008; }
  float4 v = src[off];
  u16x4 o;
  o.x = f2bf(v.x); o.y = f2bf(v.y); o.z = f2bf(v.z); o.w = f2bf(v.w);
  reinterpret_cast<u16x4*>(outbase)[i] = o;
}

// ---------------- async global->LDS helper ----------------
__device__ __forceinline__ void gld_lds16(const void* g, void* l) {
  auto gp = (__attribute__((address_space(1))) char*)(unsigned long long)g;
  auto lp = (__attribute__((address_space(3))) char*)(unsigned int)(unsigned long long)l;
  __builtin_amdgcn_global_load_lds(gp, lp, 16, 0, 0);
}

// ---------------- GEMM (2-phase dbuf, XCD-swizzled): C = A[M][1024] * B[N][1024]^T ----
// MODE 1: f32 row-major out (gemm_out, N=1024, grid 256)
// MODE 2: qkv mode (N=3072, grid 768): nt<16 Q/K bf16 row-major; nt>=16 V transposed
//         into vt[b][h][d][t] via LDS transpose (coalesced 16B stores).
template <int MODE>
__global__ __launch_bounds__(256) void gemm2(const u16* __restrict__ A,
                                             const u16* __restrict__ B,
                                             void* __restrict__ Cv,
                                             u16* __restrict__ vto,
                                             int N) {
  // smem: As[2][4096] u16 (16KB) ++ Bs[2][4096] u16 (16KB); V-transpose overlays 128x136
  __shared__ __align__(16) u16 smem[17408];
  u16* As = smem;
  u16* Bs = smem + 8192;
  const int K = 1024;

  // XCD-aware bijective swizzle (grid % 8 == 0): each XCD owns a contiguous nt slice
  const int bid = blockIdx.x;
  const int cpx = gridDim.x >> 3;
  const int swz = (bid & 7) * cpx + (bid >> 3);
  const int nt = swz >> 5, mt = swz & 31;   // 32 mt tiles (M=4096)

  const int tid = threadIdx.x;
  const int lane = tid & 63;
  const int w = tid >> 6;
  const int wr = w >> 1, wc = w & 1;
  const int lrow = lane & 15, kg = lane >> 4;
  const u16* Ag = A + (size_t)(mt * 128) * K;
  const u16* Bg = B + (size_t)(nt * 128) * K;

  f32x4 acc[4][4];
#pragma unroll
  for (int i = 0; i < 4; ++i)
#pragma unroll
    for (int j = 0; j < 4; ++j) {
      f32x4 z = {0.f, 0.f, 0.f, 0.f};
      acc[i][j] = z;
    }

  const int e0 = tid * 8;
  const int row0 = e0 >> 5, kc0 = e0 & 31;
  const int row1 = row0 + 64, kc1 = kc0;
  const int ldsoff0 = (tid & ~63) * 16;
  const int ldsoff1 = (256 + (tid & ~63)) * 16;

  // prologue: stage K-tile 0 into buf 0, then drain
  gld_lds16(Ag + (size_t)row0 * K + kc0, (char*)As + ldsoff0);
  gld_lds16(Ag + (size_t)row1 * K + kc1, (char*)As + ldsoff1);
  gld_lds16(Bg + (size_t)row0 * K + kc0, (char*)Bs + ldsoff0);
  gld_lds16(Bg + (size_t)row1 * K + kc1, (char*)Bs + ldsoff1);
  __syncthreads();

  int cur = 0;
  for (int k0 = 0; k0 < K; k0 += 32) {
    if (k0 + 32 < K) {   // issue next-tile staging EARLY; drains at end-of-iter barrier
      const int nb = (cur ^ 1) * 8192;
      gld_lds16(Ag + (size_t)row0 * K + k0 + 32 + kc0, (char*)As + nb + ldsoff0);
      gld_lds16(Ag + (size_t)row1 * K + k0 + 32 + kc1, (char*)As + nb + ldsoff1);
      gld_lds16(Bg + (size_t)row0 * K + k0 + 32 + kc0, (char*)Bs + nb + ldsoff0);
      gld_lds16(Bg + (size_t)row1 * K + k0 + 32 + kc1, (char*)Bs + nb + ldsoff1);
    }
    const int cb = cur * 4096;
    s16x8 a[4], b[4];
#pragma unroll
    for (int mf = 0; mf < 4; ++mf)
      a[mf] = *(const s16x8*)&As[cb + (wr * 64 + mf * 16 + lrow) * 32 + 8 * kg];
#pragma unroll
    for (int nf = 0; nf < 4; ++nf)
      b[nf] = *(const s16x8*)&Bs[cb + (wc * 64 + nf * 16 + lrow) * 32 + 8 * kg];
#pragma unroll
    for (int mf = 0; mf < 4; ++mf)
#pragma unroll
      for (int nf = 0; nf < 4; ++nf)
        acc[mf][nf] = __builtin_amdgcn_mfma_f32_16x16x32_bf16(a[mf], b[nf], acc[mf][nf], 0, 0, 0);
    __syncthreads();   // vmcnt(0)+lgkmcnt(0)+barrier: prefetch drained AFTER compute
    cur ^= 1;
  }

  if (MODE == 1) {
    float* C = (float*)Cv;
#pragma unroll
    for (int mf = 0; mf < 4; ++mf)
#pragma unroll
      for (int nf = 0; nf < 4; ++nf)
#pragma unroll
        for (int j = 0; j < 4; ++j) {
          int r = mt * 128 + wr * 64 + mf * 16 + 4 * kg + j;
          int c = nt * 128 + wc * 64 + nf * 16 + lrow;
          C[(size_t)r * N + c] = acc[mf][nf][j];
        }
  } else if (nt < 16) {   // Q,K thirds: row-major bf16
    u16* qkvo = (u16*)Cv;
#pragma unroll
    for (int mf = 0; mf < 4; ++mf)
#pragma unroll
      for (int nf = 0; nf < 4; ++nf)
#pragma unroll
        for (int j = 0; j < 4; ++j) {
          int r = mt * 128 + wr * 64 + mf * 16 + 4 * kg + j;
          int c = nt * 128 + wc * 64 + nf * 16 + lrow;
          qkvo[(size_t)r * QKVN_ + c] = f2bf(acc[mf][nf][j]);
        }
  } else {                // V third: LDS transpose -> coalesced stores into vt[b][h][d][t]
    // Vlds[c_local][r_local], pad 136 (272B rows, 16B-aligned, <=2-way banks)
    u16* Vlds = smem;
#pragma unroll
    for (int mf = 0; mf < 4; ++mf)
#pragma unroll
      for (int nf = 0; nf < 4; ++nf) {
        const int cl = wc * 64 + nf * 16 + lrow;
        const int rl = wr * 64 + mf * 16 + 4 * kg;
#pragma unroll
        for (int j = 0; j < 4; ++j)
          Vlds[cl * 136 + rl + j] = f2bf(acc[mf][nf][j]);
      }
    __syncthreads();
    const int c16 = tid >> 4, chunk = tid & 15;
    const int bb = mt >> 4;
    const int tb = (mt & 15) * 128 + chunk * 8;
#pragma unroll
    for (int pass = 0; pass < 8; ++pass) {
      const int cl = pass * 16 + c16;
      const int cg = nt * 128 + cl;             // 2048..3071
      const int hV = (cg >> 6) & 15, d = cg & 63;
      const s16x8 v = *(const s16x8*)&Vlds[cl * 136 + chunk * 8];
      *(s16x8*)(vto + ((size_t)((bb * 16 + hV) * 64 + d)) * T_ + tb) = v;
    }
  }
}

// ---------------- causal flash attention (paired q-tiles, uniform blocks) ----------------
// 512 blocks (16 pairs x 32 bh), 256 threads = 2 q-subwaves x 2 kv-parities.
// Block handles q-tiles jt = 31-p then p (64 rows each) -> 17 staging rounds uniform.
// K/V double-buffered in 64 KB LDS (slot^row&7 swizzle), kv-split-2 merge per phase.
__global__ __launch_bounds__(256, 2) void attn_fwd(const u16* __restrict__ qkv,
                                                   const u16* __restrict__ vt,
                                                   u16* __restrict__ o) {
  const int gid = blockIdx.x;
  const int pr = gid >> 5;             // 0..15
  const int bh = gid & 31;
  const int b = bh >> 4, h = bh & 15;
  const int tid = threadIdx.x;
  const int lane = tid & 63;
  const int qw = (tid >> 6) & 1;       // q-subwave (32 rows)
  const int kvg = tid >> 7;            // kv parity
  const int l31 = lane & 31, hi = lane >> 5;

  // K: smem + buf*16384 + par*8192 ; V: +32768 same
  __shared__ __align__(16) char smem[65536];

  const int row_s = tid >> 3, slot_s = tid & 7;
  const u16* Kbase = qkv + (size_t)(b * T_) * QKVN_ + 1024 + h * 64;
  const u16* Vbase = vt + (size_t)(bh * 64) * T_;
  const u16* KgA = Kbase + (size_t)row_s * QKVN_ + slot_s * 8;
  const u16* KgB = KgA + (size_t)32 * QKVN_;
  const u16* VgA = Vbase + (size_t)row_s * T_ + slot_s * 8;
  const u16* VgB = VgA + (size_t)32 * T_;
  const int dstA = row_s * 128 + ((slot_s ^ (row_s & 7)) << 4);  // +4096 for chunk B

  const int rbyte = l31 * 128;
  const int xsw = l31 & 7;
  const float CEXP = 0.18033688011112042f;  // (1/8) * log2(e)

  for (int ph = 0; ph < 2; ++ph) {
    const int jt = (ph == 0) ? (31 - pr) : pr;
    const int nt = jt + 1;
    const int nrt = (nt + 1) >> 1;
    const int qrow0 = 64 * jt + 32 * qw;

    // Q fragments: lane (l31,hi) holds Q[qrow0+l31][16*ksl + 8*hi .. +8]
    s16x8 qf[4];
    {
      const u16* qp = qkv + (size_t)(b * T_ + qrow0 + l31) * QKVN_ + h * 64 + 8 * hi;
#pragma unroll
      for (int ksl = 0; ksl < 4; ++ksl)
        qf[ksl] = *(const s16x8*)(qp + 16 * ksl);
    }

    f32x16 o0v, o1v;
#pragma unroll
    for (int r = 0; r < 16; ++r) { o0v[r] = 0.f; o1v[r] = 0.f; }
    float mrun = -__builtin_inff(), lrun = 0.0f;

    __syncthreads();   // smem free (prev phase merge fully read)
    // prologue: stage tiles 0 (and 1) into buf 0
    *(s16x8*)(smem + dstA)                 = *(const s16x8*)KgA;
    *(s16x8*)(smem + 4096 + dstA)          = *(const s16x8*)KgB;
    *(s16x8*)(smem + 32768 + dstA)         = *(const s16x8*)VgA;
    *(s16x8*)(smem + 32768 + 4096 + dstA)  = *(const s16x8*)VgB;
    if (nt > 1) {
      *(s16x8*)(smem + 8192 + dstA)                = *(const s16x8*)(KgA + (size_t)64 * QKVN_);
      *(s16x8*)(smem + 8192 + 4096 + dstA)         = *(const s16x8*)(KgB + (size_t)64 * QKVN_);
      *(s16x8*)(smem + 32768 + 8192 + dstA)        = *(const s16x8*)(VgA + 64);
      *(s16x8*)(smem + 32768 + 8192 + 4096 + dstA) = *(const s16x8*)(VgB + 64);
    }

    int cur = 0;
    for (int r = 0; r < nrt; ++r) {
      const int t = 2 * r + kvg;
      const bool pe = (2 * r + 2 < nt), po = (2 * r + 3 < nt);
      s16x8 ke0, ke1, ve0, ve1, ko0, ko1, vo0, vo1;
      if (pe) {                         // issue next-round loads early
        const size_t kofs = (size_t)(2 * r + 2) * 64 * QKVN_;
        const int vofs = (2 * r + 2) * 64;
        ke0 = *(const s16x8*)(KgA + kofs);
        ke1 = *(const s16x8*)(KgB + kofs);
        ve0 = *(const s16x8*)(VgA + vofs);
        ve1 = *(const s16x8*)(VgB + vofs);
      }
      if (po) {
        const size_t kofs = (size_t)(2 * r + 3) * 64 * QKVN_;
        const int vofs = (2 * r + 3) * 64;
        ko0 = *(const s16x8*)(KgA + kofs);
        ko1 = *(const s16x8*)(KgB + kofs);
        vo0 = *(const s16x8*)(VgA + vofs);
        vo1 = *(const s16x8*)(VgB + vofs);
      }
      __syncthreads();

      if (t < nt) {
        const char* Kc = smem + cur * 16384 + kvg * 8192;
        const char* Vc = smem + 32768 + cur * 16384 + kvg * 8192;
        const bool isdiag = (t == nt - 1);
        const bool two = !(isdiag && qw == 0);

        // ---- QK^T (swapped): lane holds q = qrow0+l31 ----
        f32x16 s0v, s1v;
#pragma unroll
        for (int rr = 0; rr < 16; ++rr) { s0v[rr] = 0.f; s1v[rr] = 0.f; }
        __builtin_amdgcn_s_setprio(1);
#pragma unroll
        for (int ksl = 0; ksl < 4; ++ksl) {
          const s16x8 kf = *(const s16x8*)(Kc + rbyte + (((2 * ksl + hi) ^ xsw) << 4));
          s0v = __builtin_amdgcn_mfma_f32_32x32x16_bf16(kf, qf[ksl], s0v, 0, 0, 0);
        }
        if (two) {
#pragma unroll
          for (int ksl = 0; ksl < 4; ++ksl) {
            const s16x8 kf = *(const s16x8*)(Kc + 4096 + rbyte + (((2 * ksl + hi) ^ xsw) << 4));
            s1v = __builtin_amdgcn_mfma_f32_32x32x16_bf16(kf, qf[ksl], s1v, 0, 0, 0);
          }
        }
        __builtin_amdgcn_s_setprio(0);

        // ---- causal mask (diagonal tile only) ----
        if (isdiag) {
          const int thr = 32 * qw + l31;
#pragma unroll
          for (int rr = 0; rr < 16; ++rr) {
            const int kvl = 4 * hi + (rr & 3) + 8 * (rr >> 2);
            if (kvl > thr) s0v[rr] = -__builtin_inff();
            if (two && kvl + 32 > thr) s1v[rr] = -__builtin_inff();
          }
        }

        // ---- online softmax, per-lane ----
        float mloc = s0v[0];
#pragma unroll
        for (int rr = 1; rr < 16; ++rr) mloc = fmaxf(mloc, s0v[rr]);
        if (two) {
#pragma unroll
          for (int rr = 0; rr < 16; ++rr) mloc = fmaxf(mloc, s1v[rr]);
        }
        mloc = fmaxf(mloc, __shfl_xor(mloc, 32));

        const bool needfull = !((mloc - mrun) * CEXP <= 8.0f);
        if (__any(needfull)) {
          const float newm = fmaxf(mrun, mloc);
          const float sc = fexp2((mrun - newm) * CEXP);
          mrun = newm;
          lrun *= sc;
          o0v *= sc;
          o1v *= sc;
        }
        const float msc = mrun * CEXP;

        float rs = 0.0f;
        u32 pd0[8], pd1[8];
#pragma unroll
        for (int ri = 0; ri < 8; ++ri) {
          const float p0 = fexp2(__builtin_fmaf(s0v[2 * ri], CEXP, -msc));
          const float p1 = fexp2(__builtin_fmaf(s0v[2 * ri + 1], CEXP, -msc));
          rs += p0 + p1;
          pd0[ri] = cvtpk(p0, p1);
        }
        if (two) {
#pragma unroll
          for (int ri = 0; ri < 8; ++ri) {
            const float p0 = fexp2(__builtin_fmaf(s1v[2 * ri], CEXP, -msc));
            const float p1 = fexp2(__builtin_fmaf(s1v[2 * ri + 1], CEXP, -msc));
            rs += p0 + p1;
            pd1[ri] = cvtpk(p0, p1);
          }
        }
        rs += __shfl_xor(rs, 32);
        lrun += rs;

        // ---- PV: rebuild B-fragments in-register, accumulate O^T ----
        __builtin_amdgcn_s_setprio(1);
#pragma unroll
        for (int kk = 0; kk < 4; ++kk) {
          if (kk >= 2 && !two) break;
          u32 x0, y0, x1, y1;
          if (kk == 0)      { x0 = pd0[0]; y0 = pd0[2]; x1 = pd0[1]; y1 = pd0[3]; }
          else if (kk == 1) { x0 = pd0[4]; y0 = pd0[6]; x1 = pd0[5]; y1 = pd0[7]; }
          else if (kk == 2) { x0 = pd1[0]; y0 = pd1[2]; x1 = pd1[1]; y1 = pd1[3]; }
          else              { x0 = pd1[4]; y0 = pd1[6]; x1 = pd1[5]; y1 = pd1[7]; }
          asm volatile("v_permlane32_swap_b32 %0, %1" : "+v"(x0), "+v"(y0));
          asm volatile("v_permlane32_swap_b32 %0, %1" : "+v"(x1), "+v"(y1));
          u32 pw[4] = {x0, x1, y0, y1};
          const s16x8 pf = *(const s16x8*)pw;
          const s16x8 vf0 = *(const s16x8*)(Vc + rbyte + (((2 * kk + hi) ^ xsw) << 4));
          const s16x8 vf1 = *(const s16x8*)(Vc + 4096 + rbyte + (((2 * kk + hi) ^ xsw) << 4));
          o0v = __builtin_amdgcn_mfma_f32_32x32x16_bf16(vf0, pf, o0v, 0, 0, 0);
          o1v = __builtin_amdgcn_mfma_f32_32x32x16_bf16(vf1, pf, o1v, 0, 0, 0);
        }
        __builtin_amdgcn_s_setprio(0);
      }

      if (pe) {                         // write-late into the other buffer set
        const int nb = (cur ^ 1) * 16384;
        *(s16x8*)(smem + nb + dstA)                = ke0;
        *(s16x8*)(smem + nb + 4096 + dstA)         = ke1;
        *(s16x8*)(smem + 32768 + nb + dstA)        = ve0;
        *(s16x8*)(smem + 32768 + nb + 4096 + dstA) = ve1;
      }
      if (po) {
        const int nb = (cur ^ 1) * 16384 + 8192;
        *(s16x8*)(smem + nb + dstA)                = ko0;
        *(s16x8*)(smem + nb + 4096 + dstA)         = ko1;
        *(s16x8*)(smem + 32768 + nb + dstA)        = vo0;
        *(s16x8*)(smem + 32768 + nb + 4096 + dstA) = vo1;
      }
      cur ^= 1;
    }

    // ---- merge kv-split pair partials (reuse LDS), write O ----
    __syncthreads();
    float* Om = (float*)smem + qw * 2048;            // 32 x 64 f32 per qw
    float* Mf = (float*)(smem + 16384) + qw * 64;
    float* Lf = (float*)(smem + 16896) + qw * 64;
    if (kvg == 1) {
#pragma unroll
      for (int rr = 0; rr < 16; ++rr) {
        Om[rr * 64 + lane] = o0v[rr];
        Om[(16 + rr) * 64 + lane] = o1v[rr];
      }
      Mf[lane] = mrun;
      Lf[lane] = lrun;
    }
    __syncthreads();
    if (kvg == 0) {
      const float mA = Mf[lane];
      const float lA = Lf[lane];
      const float m2 = fmaxf(mrun, mA);
      const float sB = fexp2((mrun - m2) * CEXP);
      const float sA = fexp2((mA - m2) * CEXP);
      const float linv = 1.0f / (lrun * sB + lA * sA);
      u16* orow = o + (size_t)(b * T_ + qrow0 + l31) * DIM_ + h * 64;
#pragma unroll
      for (int ri = 0; ri < 8; ++ri) {
        const int dbase0 = 4 * hi + 8 * (ri >> 1) + 2 * (ri & 1);
        const float a0 = (o0v[2 * ri] * sB + Om[(2 * ri) * 64 + lane] * sA) * linv;
        const float a1 = (o0v[2 * ri + 1] * sB + Om[(2 * ri + 1) * 64 + lane] * sA) * linv;
        const float c0 = (o1v[2 * ri] * sB + Om[(16 + 2 * ri) * 64 + lane] * sA) * linv;
        const float c1 = (o1v[2 * ri + 1] * sB + Om[(16 + 2 * ri + 1) * 64 + lane] * sA) * linv;
        *(u32*)(orow + dbase0) = cvtpk(a0, a1);
        *(u32*)(orow + 32 + dbase0) = cvtpk(c0, c1);
      }
    }
  }
}

// ---------------- launch ----------------
extern "C" void kernel_launch(void* const* d_in, const int* in_sizes, int n_in,
                              void* d_out, int out_size, void* d_ws, size_t ws_size,
                              hipStream_t stream) {
  const float* x = (const float*)d_in[0];
  const float* w_qkv = (const float*)d_in[1];
  const float* w_out = (const float*)d_in[2];
  char* ws = (char*)d_ws;
  u16* xb    = (u16*)(ws + 0);          // 8,388,608
  u16* wqkvb = (u16*)(ws + 8388608);    // 6,291,456
  u16* woutb = (u16*)(ws + 14680064);   // 2,097,152
  u16* qkvb  = (u16*)(ws + 16777216);   // 25,165,824 (V third unused)
  u16* vtb   = (u16*)(ws + 41943040);   // 8,388,608
  u16* attno = (u16*)(ws + 50331648);   // 8,388,608

  cvt_all<<<8192, 256, 0, stream>>>(x, w_qkv, w_out, xb);
  gemm2<2><<<768, 256, 0, stream>>>(xb, wqkvb, qkvb, vtb, QKVN_);
  attn_fwd<<<512, 256, 0, stream>>>(qkvb, vtb, attno);
  gemm2<1><<<256, 256, 0, stream>>>(attno, woutb, d_out, nullptr, DIM_);
}